// Round 2
// baseline (266.584 us; speedup 1.0000x reference)
//
#include <hip/hip_runtime.h>

#define NUM_ACT 64
#define SPLINE_SIZE 51
// x is [32, 64, 128, 128]: H*W = 16384 elems/channel -> 8 blocks of
// 256 thr x 8 elems per channel; channel index is block-uniform.
//
// THIS ROUND IS AN A/B MEASUREMENT ROUND.
// Graph = [poison fills] + spline_b (candidate) + spline_a (round-0 verbatim).
// Round 0 established fills + t_A = 221.6 us, so dur_us - 221.6 == t_B:
// a direct measurement of the candidate's absolute kernel time, which the
// top-5 counter table cannot show (fills dominate it).
// spline_a runs LAST so the committed output is bit-identical to round 0.

typedef float f32x4 __attribute__((ext_vector_type(4)));
typedef float f32x2 __attribute__((ext_vector_type(2)));

// ---------- Variant B (candidate): fused-table, 1x ds_read_b64 + 1 fma ----------
// Table entry i = (coef[i]*rs, (coef[i+1]-coef[i])*rs): halves the LDS
// instruction count (1 b64 gather vs 2 b32 gathers with clustered-index
// bank conflicts) and collapses the lerp to a single fmaf.
__global__ __launch_bounds__(256) void spline_b(
    const f32x4* __restrict__ x4,
    const float* __restrict__ coef,
    const float* __restrict__ scale,
    f32x4* __restrict__ out4)
{
    __shared__ f32x2 lut[SPLINE_SIZE - 1];   // 50 entries, 400 B, 8B-aligned

    int c = (blockIdx.x >> 3) & (NUM_ACT - 1);   // block-uniform channel
    float s  = scale[c];
    float rs = 1.0f / s;

    if (threadIdx.x < SPLINE_SIZE - 1) {
        float a = coef[c * SPLINE_SIZE + threadIdx.x];
        float b = coef[c * SPLINE_SIZE + threadIdx.x + 1];
        f32x2 e; e[0] = a * rs; e[1] = (b - a) * rs;   // exact for s==1
        lut[threadIdx.x] = e;
    }

    const float sg = s * 6.25f;   // fold *s and *(1/grid); 6.25f == fl(1/0.16f)
    __syncthreads();

    int base = blockIdx.x * 512 + threadIdx.x;

#pragma unroll
    for (int j = 0; j < 2; ++j) {
        int i = base + j * 256;
        f32x4 xv = __builtin_nontemporal_load(&x4[i]);
        f32x4 ov;
#pragma unroll
        for (int k = 0; k < 4; ++k) {
            float t = xv[k] * sg;
            // floor-then-int-clamp == reference clamp-then-floor (validated
            // boundary cases in round 0); fr from UNclamped t.
            int fl = (int)floorf(t);
            fl = min(max(fl, -(SPLINE_SIZE / 2)), SPLINE_SIZE / 2 - 1); // [-25,24]
            float fr = t - (float)fl;
            f32x2 cd = lut[fl + SPLINE_SIZE / 2];    // one ds_read_b64
            ov[k] = fmaf(cd[1], fr, cd[0]);          // c0 + (c1-c0)*fr
        }
        __builtin_nontemporal_store(ov, &out4[i]);
    }
}

// ---------- Variant A: round-0 kernel VERBATIM (runs last, defines output) ----------
__global__ __launch_bounds__(256) void spline_a(
    const f32x4* __restrict__ x4,
    const float* __restrict__ coef,
    const float* __restrict__ scale,
    f32x4* __restrict__ out4)
{
    __shared__ float lcoef[SPLINE_SIZE];

    int c = (blockIdx.x >> 3) & (NUM_ACT - 1);   // block-uniform channel

    if (threadIdx.x < SPLINE_SIZE)
        lcoef[threadIdx.x] = coef[c * SPLINE_SIZE + threadIdx.x];

    float s  = scale[c];        // scalar load (c is SGPR-uniform)
    float rs = 1.0f / s;

    __syncthreads();

    const float inv_grid = 6.25f;   // == fl(1/0.16f) exactly

    int base = blockIdx.x * 512 + threadIdx.x;   // two float4s: base, base+256

#pragma unroll
    for (int j = 0; j < 2; ++j) {
        int i = base + j * 256;
        f32x4 xv = __builtin_nontemporal_load(&x4[i]);
        f32x4 ov;
#pragma unroll
        for (int k = 0; k < 4; ++k) {
            float xs = xv[k] * s;
            float t  = xs * inv_grid;
            int fl = (int)floorf(t);
            fl = min(max(fl, -(SPLINE_SIZE / 2)), SPLINE_SIZE / 2 - 1); // [-25,24]
            float fr = t - (float)fl;          // fracs from UNclamped xs
            int li = fl + SPLINE_SIZE / 2;     // [0, 49]
            float c0 = lcoef[li];
            float c1 = lcoef[li + 1];
            ov[k] = (c1 * fr + c0 * (1.0f - fr)) * rs;
        }
        __builtin_nontemporal_store(ov, &out4[i]);
    }
}

extern "C" void kernel_launch(void* const* d_in, const int* in_sizes, int n_in,
                              void* d_out, int out_size, void* d_ws, size_t ws_size,
                              hipStream_t stream) {
    const float* x     = (const float*)d_in[0];
    const float* coef  = (const float*)d_in[1];
    const float* scale = (const float*)d_in[2];
    float* out = (float*)d_out;

    int n  = in_sizes[0];          // 33,554,432 (divisible by 2048)
    int n4 = n >> 2;               // 8,388,608 float4s
    int grid = n4 / 512;           // 16384 blocks, exact

    // B first (timed add-on), A last (defines committed output, bit-identical
    // to round 0's verified result).
    spline_b<<<grid, 256, 0, stream>>>((const f32x4*)x, coef, scale, (f32x4*)out);
    spline_a<<<grid, 256, 0, stream>>>((const f32x4*)x, coef, scale, (f32x4*)out);
}

// Round 3
// 222.746 us; speedup vs baseline: 1.1968x; 1.1968x over previous
//
#include <hip/hip_runtime.h>

#define NUM_ACT 64
#define SPLINE_SIZE 51
// x is [32, 64, 128, 128]: H*W = 16384 elems/channel -> 8 blocks of
// 256 thr x 8 elems per channel; channel index is block-uniform.
//
// Fused-table variant (measured t ~= 45 us via the round-2 A/B graph:
// dur 266.6 - 221.6 baseline = t_B; vs ~58-64 us for the 2x ds_read_b32
// version). Table entry i = (coef[i]*rs, (coef[i+1]-coef[i])*rs):
//   - ONE ds_read_b64 gather per element instead of TWO ds_read_b32s with
//     clustered-index (x~N(0,1) -> li in [16,34]) bank conflicts
//   - lerp collapses to a single fmaf: c0 + (c1-c0)*fr
// 268 MB of irreducible traffic / 45 us ~= 6.0 TB/s — within ~5% of the
// 6.3 TB/s achievable copy ceiling.

typedef float f32x4 __attribute__((ext_vector_type(4)));
typedef float f32x2 __attribute__((ext_vector_type(2)));

__global__ __launch_bounds__(256) void linear_spline_kernel(
    const f32x4* __restrict__ x4,
    const float* __restrict__ coef,
    const float* __restrict__ scale,
    f32x4* __restrict__ out4)
{
    __shared__ f32x2 lut[SPLINE_SIZE - 1];   // 50 entries, 400 B, 8B-aligned

    int c = (blockIdx.x >> 3) & (NUM_ACT - 1);   // block-uniform channel
    float s  = scale[c];                         // scalar load (c is uniform)
    float rs = 1.0f / s;

    if (threadIdx.x < SPLINE_SIZE - 1) {
        float a = coef[c * SPLINE_SIZE + threadIdx.x];
        float b = coef[c * SPLINE_SIZE + threadIdx.x + 1];
        f32x2 e; e[0] = a * rs; e[1] = (b - a) * rs;   // fold /s into table (exact for s==1)
        lut[threadIdx.x] = e;
    }

    const float sg = s * 6.25f;   // fold *s and *(1/grid); 6.25f == fl(1/0.16f) exactly
    __syncthreads();

    int base = blockIdx.x * 512 + threadIdx.x;   // two float4s: base, base+256

#pragma unroll
    for (int j = 0; j < 2; ++j) {
        int i = base + j * 256;
        f32x4 xv = __builtin_nontemporal_load(&x4[i]);
        f32x4 ov;
#pragma unroll
        for (int k = 0; k < 4; ++k) {
            float t = xv[k] * sg;
            // floor-then-int-clamp == reference's clamp-then-floor at the
            // boundaries (xs>3.84 -> t>=24.000001 -> fl=24; xs<-4 ->
            // -4.0f/0.16f == -25.0f exactly -> floor == clamp == -25);
            // interior 1-ulp floor flips are continuous -> harmless.
            int fl = (int)floorf(t);
            fl = min(max(fl, -(SPLINE_SIZE / 2)), SPLINE_SIZE / 2 - 1); // [-25,24]
            float fr = t - (float)fl;                 // fracs from UNclamped t
            f32x2 cd = lut[fl + SPLINE_SIZE / 2];     // one ds_read_b64, idx in [0,49]
            ov[k] = fmaf(cd[1], fr, cd[0]);           // c0 + (c1-c0)*fr
        }
        __builtin_nontemporal_store(ov, &out4[i]);
    }
}

extern "C" void kernel_launch(void* const* d_in, const int* in_sizes, int n_in,
                              void* d_out, int out_size, void* d_ws, size_t ws_size,
                              hipStream_t stream) {
    const float* x     = (const float*)d_in[0];
    const float* coef  = (const float*)d_in[1];
    const float* scale = (const float*)d_in[2];
    float* out = (float*)d_out;

    int n  = in_sizes[0];          // 33,554,432 (divisible by 2048)
    int n4 = n >> 2;               // 8,388,608 float4s
    int grid = n4 / 512;           // 16384 blocks, exact

    linear_spline_kernel<<<grid, 256, 0, stream>>>(
        (const f32x4*)x, coef, scale, (f32x4*)out);
}